// Round 8
// baseline (283.487 us; speedup 1.0000x reference)
//
#include <hip/hip_runtime.h>
#include <math.h>

namespace {
constexpr int kB = 4096, kN = 128, kT = 20, kD = 64, kP = 8;
constexpr float kTwoPi = 6.28318530717958647692f;
constexpr float kBinW  = 0.78539816339744830962f;  // 2pi/8 in f32
}

// One WAVE per batch element. No LDS, no __syncthreads — 16 independent
// waves/CU keep the memory pipe continuously fed (R7 diagnosis: barrier-
// quantized bursts left every pipe <17% busy).
__global__ __launch_bounds__(256, 4)
void circle_wave(const float* __restrict__ ego,
                 const float* __restrict__ nei,
                 const float* __restrict__ fres,
                 const float* __restrict__ Wce,
                 const float* __restrict__ bce,
                 float* __restrict__ out) {
  const int lane = threadIdx.x & 63;
  const int w    = threadIdx.x >> 6;
  const int b    = blockIdx.x * 4 + w;    // 1024 blocks x 4 waves = 4096
  const int h    = lane & 1;              // half-trajectory (R5-proven split)
  const int m    = lane >> 1;             // neighbor-within-pass 0..31

  const float egx = ego[(size_t)b * 40 + 38];
  const float egy = ego[(size_t)b * 40 + 39];

  // ---- per-neighbor bin/dist/dir, 4 passes of 32 neighbors (all in regs)
  int   binq[4];
  float distq[4], dirq[4];
  const float4* nb4 = reinterpret_cast<const float4*>(nei) + (size_t)b * 1280;
  #pragma unroll
  for (int q = 0; q < 4; ++q) {
    const int n = q * 32 + m;
    const float4* p4 = nb4 + n * 10 + h * 5;   // 80 B contiguous per lane
    const float4 v0 = p4[0], v1 = p4[1], v2 = p4[2], v3 = p4[3], v4 = p4[4];
    float s = ((v0.x + v0.y) + (v0.z + v0.w)) + ((v1.x + v1.y) + (v1.z + v1.w))
            + ((v2.x + v2.y) + (v2.z + v2.w)) + ((v3.x + v3.y) + (v3.z + v3.w))
            + ((v4.x + v4.y) + (v4.z + v4.w));
    const float tot = s + __shfl_xor(s, 1, 64);  // full 40-float sum (R5 order)
    const float lx  = __shfl_xor(v4.z, 1, 64);   // odd lane's floats 38,39 =
    const float ly  = __shfl_xor(v4.w, 1, 64);   // last-frame x,y -> even lane
    const float rx = lx - egx, ry = ly - egy;
    const float dist = sqrtf(rx * rx + ry * ry);
    // correctly-rounded f32 atan2 via double (bit-matches ref; proven R4-R7)
    float dir = (float)atan2((double)rx, (double)ry);
    if (dir < 0.0f) dir += kTwoPi;
    int idx = (int)(dir / kBinW);                // trunc, matches astype(int32)
    if (h == 1 || tot == 0.0f) idx = -1;         // odd-lane mirror / invalid
    binq[q] = idx; distq[q] = dist; dirq[q] = dir;
  }

  // ---- per-bin scan sums via 64-lane butterflies (no LDS, no atomics)
  float cnt[kP], sd[kP], sth[kP];
  #pragma unroll
  for (int p = 0; p < kP; ++p) {
    float c = 0.f, d = 0.f, t = 0.f;
    #pragma unroll
    for (int q = 0; q < 4; ++q) {
      const bool hit = (binq[q] == p);           // odd lanes have -1: no hit
      c += hit ? 1.0f : 0.0f;
      d += hit ? distq[q] : 0.0f;
      t += hit ? dirq[q] : 0.0f;
    }
    #pragma unroll
    for (int o = 1; o < 64; o <<= 1) {
      c += __shfl_xor(c, o, 64);
      d += __shfl_xor(d, o, 64);
      t += __shfl_xor(t, o, 64);
    }
    cnt[p] = c; sd[p] = d; sth[p] = t;
  }

  // ---- resonance stream: lane = column d, 128 rows of 256 B/wave.
  // Static binq[q] indexing (outer q fully unrolled); unroll-16 inner gives
  // 16 independent 4B loads in flight per wave continuously.
  const float* rb = fres + (size_t)b * (kN * kD) + lane;
  float acc[kP];
  #pragma unroll
  for (int p = 0; p < kP; ++p) acc[p] = 0.f;
  #pragma unroll
  for (int q = 0; q < 4; ++q) {
    const int bq = binq[q];
    #pragma unroll 16
    for (int j = 0; j < 32; ++j) {
      const float v  = rb[(q * 32 + j) * kD];
      const int   bn = __shfl(bq, 2 * j, 64);    // row's bin, wave-uniform
      #pragma unroll
      for (int p = 0; p < kP; ++p)
        acc[p] += (bn == p) ? v : 0.0f;
    }
  }

  // ---- epilogue: 16 coalesced 256B stores per wave (4 KB = one batch row)
  const float w0 = Wce[lane];          // W[0][d]
  const float w1 = Wce[kD + lane];     // W[1][d]
  const float bc = bce[lane];
  float* ob = out + (size_t)b * (kP * 2 * kD);
  #pragma unroll
  for (int p = 0; p < kP; ++p) {
    const float nf = cnt[p] + 1e-4f;
    ob[p * 128 + lane] = acc[p] / nf;                    // resonance_circle
    const float s0 = sd[p] / nf, s1 = sth[p] / nf;
    ob[p * 128 + kD + lane] =
        fmaxf(fmaf(s0, w0, fmaf(s1, w1, bc)), 0.0f);     // relu(scan @ W + b)
  }
}

extern "C" void kernel_launch(void* const* d_in, const int* in_sizes, int n_in,
                              void* d_out, int out_size, void* d_ws, size_t ws_size,
                              hipStream_t stream) {
  const float* ego  = (const float*)d_in[0];
  const float* nei  = (const float*)d_in[1];
  const float* fres = (const float*)d_in[2];
  const float* Wce  = (const float*)d_in[3];
  const float* bce  = (const float*)d_in[4];
  float* out = (float*)d_out;
  hipLaunchKernelGGL(circle_wave, dim3(kB / 4), dim3(256), 0, stream,
                     ego, nei, fres, Wce, bce, out);
}

// Round 10
// 256.472 us; speedup vs baseline: 1.1053x; 1.1053x over previous
//
#include <hip/hip_runtime.h>
#include <math.h>

namespace {
constexpr int kB = 4096, kN = 128, kT = 20, kD = 64, kP = 8;
constexpr float kTwoPi = 6.28318530717958647692f;
constexpr float kBinW  = 0.78539816339744830962f;  // 2pi/8 in f32
}

// One WAVE per batch, wave-autonomous (zero __syncthreads -> no vmcnt(0)
// drains). R8 fixed: coalesced nei (16 lines/instr), float4 fres, 128 atan2,
// and a double-buffered fres stream so loads stay in flight through compute.
__global__ __launch_bounds__(256)
void circle_wstream(const float* __restrict__ ego,
                    const float* __restrict__ nei,
                    const float* __restrict__ fres,
                    const float* __restrict__ Wce,
                    const float* __restrict__ bce,
                    float* __restrict__ out) {
  const int l  = threadIdx.x & 63;
  const int wv = threadIdx.x >> 6;
  const int b  = blockIdx.x * 4 + wv;            // 1024 blocks x 4 waves

  __shared__ float s_psum[4][kN * 10];           // per-wave regions, no barriers
  __shared__ float s_last[4][kN * 2];
  __shared__ int   s_bins[4][kN];
  float* psum = s_psum[wv];
  float* last = s_last[wv];
  int*   bins = s_bins[wv];

  const float w0 = Wce[l], w1 = Wce[kD + l], bcv = bce[l];

  // ---- nei: 20 coalesced float4 loads (wave reads 1 KB per instruction)
  const float4* nb = reinterpret_cast<const float4*>(nei) + (size_t)b * 1280;
  float4 nv[20];
  #pragma unroll
  for (int k = 0; k < 20; ++k) nv[k] = nb[k * 64 + l];

  // regroup to per-neighbor via wave-local LDS (stride 10 -> 2-way, free)
  #pragma unroll
  for (int k = 0; k < 20; ++k) {
    const int j = k * 64 + l;
    const float4 v = nv[k];
    psum[j] = (v.x + v.y) + (v.z + v.w);
    const int n = j / 10;                        // 10 float4 per neighbor
    if (j - n * 10 == 9) { last[2 * n] = v.z; last[2 * n + 1] = v.w; }
  }

  // ---- issue fres chunks 0,1 NOW (independent of bins; hides under atan2)
  const float4* rb = reinterpret_cast<const float4*>(fres) + (size_t)b * 2048;
  float4 fa[8], fb[8];
  #pragma unroll
  for (int k = 0; k < 8; ++k) fa[k] = rb[k * 64 + l];
  #pragma unroll
  for (int k = 0; k < 8; ++k) fb[k] = rb[(8 + k) * 64 + l];

  // ---- two neighbors per lane: n0 = l, n1 = l + 64
  float t0 = 0.f, t1 = 0.f;
  #pragma unroll
  for (int k = 0; k < 10; ++k) {
    t0 += psum[l * 10 + k];
    t1 += psum[(l + 64) * 10 + k];
  }
  const float egx = ego[(size_t)b * 40 + 38];
  const float egy = ego[(size_t)b * 40 + 39];
  const float rx0 = last[2 * l] - egx,          ry0 = last[2 * l + 1] - egy;
  const float rx1 = last[2 * (l + 64)] - egx,   ry1 = last[2 * (l + 64) + 1] - egy;
  const float d0 = sqrtf(rx0 * rx0 + ry0 * ry0);
  const float d1 = sqrtf(rx1 * rx1 + ry1 * ry1);
  // correctly-rounded f32 atan2 via double (bit-matches ref; proven R4-R8);
  // the two calls are independent -> ILP, and fres chunk latency hides here
  float a0 = (float)atan2((double)rx0, (double)ry0);
  float a1 = (float)atan2((double)rx1, (double)ry1);
  if (a0 < 0.f) a0 += kTwoPi;
  if (a1 < 0.f) a1 += kTwoPi;
  int i0 = (int)(a0 / kBinW);                    // trunc, matches astype(int32)
  int i1 = (int)(a1 / kBinW);
  if (t0 == 0.f) i0 = -1;                        // invalid neighbor -> -1
  if (t1 == 0.f) i1 = -1;                        // (idx==8 handled by ==p tests)
  bins[l] = i0; bins[l + 64] = i1;

  // ---- per-bin scan sums over 128 neighbors: 64-lane butterflies
  float cnt[kP], sd[kP], sth[kP];
  #pragma unroll
  for (int p = 0; p < kP; ++p) {
    float c = (i0 == p ? 1.f : 0.f) + (i1 == p ? 1.f : 0.f);
    float d = (i0 == p ? d0 : 0.f) + (i1 == p ? d1 : 0.f);
    float t = (i0 == p ? a0 : 0.f) + (i1 == p ? a1 : 0.f);
    #pragma unroll
    for (int o = 1; o < 64; o <<= 1) {
      c += __shfl_xor(c, o, 64);
      d += __shfl_xor(d, o, 64);
      t += __shfl_xor(t, o, 64);
    }
    cnt[p] = c; sd[p] = d; sth[p] = t;
  }

  // ---- fres select-FMA: 32 f4/lane in 4 chunks, double-buffered fa/fb.
  // f4 index kk*64+l -> row = 4*kk + (l>>4), col-f4 = l&15; bins[row] is an
  // LDS broadcast (16 lanes same addr, 4 addrs -> conflict-free).
  float4 acc[kP];
  #pragma unroll
  for (int p = 0; p < kP; ++p) acc[p] = make_float4(0.f, 0.f, 0.f, 0.f);

#define CONSUME(BUF, BASE)                                              \
  _Pragma("unroll")                                                     \
  for (int k = 0; k < 8; ++k) {                                         \
    const int row = 4 * ((BASE) + k) + (l >> 4);                        \
    const int bn = bins[row];                                           \
    const float4 v = BUF[k];                                            \
    _Pragma("unroll")                                                   \
    for (int p = 0; p < kP; ++p) {                                      \
      const float m = (bn == p) ? 1.f : 0.f;                            \
      acc[p].x = fmaf(v.x, m, acc[p].x);                                \
      acc[p].y = fmaf(v.y, m, acc[p].y);                                \
      acc[p].z = fmaf(v.z, m, acc[p].z);                                \
      acc[p].w = fmaf(v.w, m, acc[p].w);                                \
    }                                                                   \
  }

  CONSUME(fa, 0)                                 // chunk 0 (issued early)
  #pragma unroll
  for (int k = 0; k < 8; ++k) fa[k] = rb[(16 + k) * 64 + l];  // refill: chunk 2
  CONSUME(fb, 8)                                 // chunk 1 (in flight since atan2)
  #pragma unroll
  for (int k = 0; k < 8; ++k) fb[k] = rb[(24 + k) * 64 + l];  // refill: chunk 3
  CONSUME(fa, 16)                                // chunk 2
  CONSUME(fb, 24)                                // chunk 3
#undef CONSUME

  // reduce over the 4 row-groups (lane bits 4,5): full 128-row sums per col
  #pragma unroll
  for (int p = 0; p < kP; ++p) {
    #pragma unroll
    for (int o = 16; o < 64; o <<= 1) {
      acc[p].x += __shfl_xor(acc[p].x, o, 64);
      acc[p].y += __shfl_xor(acc[p].y, o, 64);
      acc[p].z += __shfl_xor(acc[p].z, o, 64);
      acc[p].w += __shfl_xor(acc[p].w, o, 64);
    }
  }

  // ---- epilogue: one 1024-float batch row
  float* ob = out + (size_t)b * (kP * 2 * kD);
  #pragma unroll
  for (int p = 0; p < kP; ++p) {
    const float nf = cnt[p] + 1e-4f;
    if (l < 16) {                                // resonance_circle: 16 f4 = 256 B
      float4 o = acc[p];
      o.x /= nf; o.y /= nf; o.z /= nf; o.w /= nf;
      reinterpret_cast<float4*>(ob + p * 128)[l] = o;
    }
    const float s0 = sd[p] / nf, s1 = sth[p] / nf;
    ob[p * 128 + kD + l] =                       // f_scan: 64 scalars = 256 B
        fmaxf(fmaf(s0, w0, fmaf(s1, w1, bcv)), 0.0f);
  }
}

extern "C" void kernel_launch(void* const* d_in, const int* in_sizes, int n_in,
                              void* d_out, int out_size, void* d_ws, size_t ws_size,
                              hipStream_t stream) {
  const float* ego  = (const float*)d_in[0];
  const float* nei  = (const float*)d_in[1];
  const float* fres = (const float*)d_in[2];
  const float* Wce  = (const float*)d_in[3];
  const float* bce  = (const float*)d_in[4];
  float* out = (float*)d_out;
  hipLaunchKernelGGL(circle_wstream, dim3(kB / 4), dim3(256), 0, stream,
                     ego, nei, fres, Wce, bce, out);
}